// Round 9
// baseline (13104.153 us; speedup 1.0000x reference)
//
#include <hip/hip_runtime.h>

#define B_  4096
#define T_  2048
#define H1_ 32
#define H2_ 16
#define RPB 4   // independent rows (1 per wave) per 256-thread block; waves never interact

#define LOG2E     1.44269504088896340736f
#define TWOLOG2E  2.88539008177792681472f

typedef float f32x2 __attribute__((ext_vector_type(2)));
typedef float f32x4 __attribute__((ext_vector_type(4)));

// packed fp32 fma (R5-proven exact; lowers to v_pk_fma_f32)
#if defined(__has_builtin)
#if __has_builtin(__builtin_elementwise_fma)
#define PKFMA(acc, a, b) (acc) = __builtin_elementwise_fma((a), (b), (acc))
#endif
#endif
#ifndef PKFMA
#define PKFMA(acc, a, b) (acc) = (a) * (b) + (acc)
#endif

// Wave-local LDS ordering fences (replace __syncthreads; waves share nothing):
// FENCE_HW: compiler memory fence + wait for outstanding DS ops (the sh write)
//           to complete before subsequent ds_reads issue. No s_barrier, no
//           vmcnt drain -> x prefetch stays in flight, waves stay decoupled.
// FENCE_SW: zero-instruction compiler fence; stops TBAA-blind reordering of
//           float stores vs f32x4 loads across step boundaries (R8 failure).
#define FENCE_HW() asm volatile("s_waitcnt lgkmcnt(0)" ::: "memory")
#define FENCE_SW() asm volatile("" ::: "memory")

__device__ __forceinline__ float sig_core(float z) {
    return __builtin_amdgcn_rcpf(1.0f + __builtin_amdgcn_exp2f(-z));
}

// ---- ws layout (floats), all pre-scaled by log2e / 2log2e ----
#define WS_W1   0
#define WS_W2A  4096
#define WS_W2B  6144
#define WS_WX   7168
#define WS_B1   7296
#define WS_B2   7424
#define WS_N    7488

// layer1 gate rows: [0,32)=i [32,64)=f [64,96)=g(tanh) [96,128)=o
__device__ __forceinline__ float scale1(int r) {
    return (r >= 64 && r < 96) ? TWOLOG2E : LOG2E;
}
// layer2 gate rows: [0,16)=i [16,32)=f [32,48)=g(tanh) [48,64)=o
__device__ __forceinline__ float scale2(int r) {
    return ((r >> 4) == 2) ? TWOLOG2E : LOG2E;
}

__global__ __launch_bounds__(256) void prescale_kernel(
    const float* __restrict__ W_ih1, const float* __restrict__ W_hh1,
    const float* __restrict__ b_ih1, const float* __restrict__ b_hh1,
    const float* __restrict__ W_ih2, const float* __restrict__ W_hh2,
    const float* __restrict__ b_ih2, const float* __restrict__ b_hh2,
    float* __restrict__ ws)
{
    const int i = blockIdx.x * 256 + threadIdx.x;
    if (i >= WS_N) return;
    float v;
    if (i < WS_W2A) {                       // W_hh1
        v = W_hh1[i] * scale1(i >> 5);
    } else if (i < WS_W2B) {                // W_ih2
        const int j = i - WS_W2A;
        v = W_ih2[j] * scale2(j >> 5);
    } else if (i < WS_WX) {                 // W_hh2
        const int j = i - WS_W2B;
        v = W_hh2[j] * scale2(j >> 4);
    } else if (i < WS_B1) {                 // W_ih1
        const int r = i - WS_WX;
        v = W_ih1[r] * scale1(r);
    } else if (i < WS_B2) {                 // b1 fused
        const int r = i - WS_B1;
        v = (b_ih1[r] + b_hh1[r]) * scale1(r);
    } else {                                // b2 fused
        const int r = i - WS_B2;
        v = (b_ih2[r] + b_hh2[r]) * scale2(r);
    }
    ws[i] = v;
}

__global__ __launch_bounds__(64 * RPB, 4) void lstm_deep_kernel(
    const float* __restrict__ x,
    const float* __restrict__ ws,     // pre-scaled weights/biases
    const float* __restrict__ W_out,
    const float* __restrict__ b_out,
    float* __restrict__ out)
{
    const int tid  = threadIdx.x;
    const int lane = tid & 63;
    const int wid  = tid >> 6;                 // wave within block
    const int row  = blockIdx.x * RPB + wid;   // batch row (1 wave : 1 row)

    // per-wave PRIVATE LDS slices; ordering by wave-local fences (see above)
    __shared__ __align__(16) float sh1[RPB][H1_];
    __shared__ __align__(16) float sh2[RPB][2][H2_];

    // ---- per-lane weights from pre-scaled ws (bare loads; cheap L1 remat) ----
    const int ga = lane;        // layer1 rows: i (low) / f (high)
    const int gb = 64 + lane;   // layer1 rows: g (low, tanh) / o (high)

    const f32x2* W1p  = reinterpret_cast<const f32x2*>(ws + WS_W1);
    const f32x2* W2ap = reinterpret_cast<const f32x2*>(ws + WS_W2A);
    const f32x2* W2bp = reinterpret_cast<const f32x2*>(ws + WS_W2B);

    f32x2 w1a[H1_ / 2], w1b[H1_ / 2];
    #pragma unroll
    for (int j = 0; j < H1_ / 2; ++j) {
        w1a[j] = W1p[ga * (H1_ / 2) + j];
        w1b[j] = W1p[gb * (H1_ / 2) + j];
    }
    f32x2 w2a[H1_ / 2];
    #pragma unroll
    for (int j = 0; j < H1_ / 2; ++j) w2a[j] = W2ap[lane * (H1_ / 2) + j];
    f32x2 w2b[H2_ / 2];
    #pragma unroll
    for (int j = 0; j < H2_ / 2; ++j) w2b[j] = W2bp[lane * (H2_ / 2) + j];

    const float wxa = ws[WS_WX + ga];
    const float wxb = ws[WS_WX + gb];
    const float ba  = ws[WS_B1 + ga];
    const float bb  = ws[WS_B1 + gb];
    const float b2  = ws[WS_B2 + lane];

    // activation combine constants: act = fma(sc, sigmoid_core, of)
    const bool  low  = (lane < 32);
    const int   gt   = lane >> 4;
    const float sc1b = low ? 2.0f : 1.0f;
    const float of1b = low ? -1.0f : 0.0f;
    const float sc2c = (gt == 2) ? 2.0f : 1.0f;
    const float of2c = (gt == 2) ? -1.0f : 0.0f;

    const int   u2   = lane & 15;
    const float wout = W_out[u2];
    const float bout = b_out[0];

    // ---- state ----
    float c1 = 0.0f;   // valid in high lanes (unit lane-32)
    float c2 = 0.0f;   // replicated x4 (unit lane&15)
    if (lane < H1_) sh1[wid][lane] = 0.0f;
    if (lane < H2_) { sh2[wid][0][lane] = 0.0f; sh2[wid][1][lane] = 0.0f; }
    FENCE_HW();   // init visible before first-step reads (wave-local)

    const f32x4* __restrict__ xr4  = reinterpret_cast<const f32x4*>(x + (size_t)row * T_);
    float*       __restrict__ orow = out + (size_t)row * T_;

    // returns un-reduced y partial (wout * h2v); reduction batched per 4 steps
    auto step = [&](float xt, int par) -> float {
        // ---- layer 1: 2 gate rows/lane, packed chains over h1_{t-1} (LDS bcast) ----
        f32x2 A  = {__builtin_fmaf(wxa, xt, ba), 0.0f};
        f32x2 Bv = {__builtin_fmaf(wxb, xt, bb), 0.0f};
        {
            const f32x4* p4 = reinterpret_cast<const f32x4*>(sh1[wid]);
            #pragma unroll
            for (int q = 0; q < H1_ / 4; ++q) {
                const f32x4 v = p4[q];
                const f32x2 h01 = {v.x, v.y};
                const f32x2 h23 = {v.z, v.w};
                PKFMA(A,  w1a[2 * q],     h01);
                PKFMA(Bv, w1b[2 * q],     h01);
                PKFMA(A,  w1a[2 * q + 1], h23);
                PKFMA(Bv, w1b[2 * q + 1], h23);
            }
        }
        const float acca = A.x + A.y;
        const float accb = Bv.x + Bv.y;

        const float sa = sig_core(acca);                             // sig(i) | sig(f)
        const float sb = __builtin_fmaf(sc1b, sig_core(accb), of1b); // tanh(g) | sig(o)
        const float pv = __shfl_xor(sa * sb, 32);   // high lanes get sig(i)*tanh(g)
        c1 = __builtin_fmaf(sa, c1, pv);            // high: sig(f)*c1 + p
        const float tc1 = __builtin_fmaf(2.0f, sig_core(TWOLOG2E * c1), -1.0f);
        const float h1new = sb * tc1;               // valid lanes 32..63

        if (lane >= 32) sh1[wid][lane - 32] = h1new;
        FENCE_HW();   // sh1 write complete + no read hoisted above it

        // ---- layer 2: 1 gate row/lane, packed chains over [h1_t ; h2_{t-1}] ----
        f32x2 E = {b2, 0.0f};
        f32x2 F = {0.0f, 0.0f};
        {
            const f32x4* p4 = reinterpret_cast<const f32x4*>(sh1[wid]);
            #pragma unroll
            for (int q = 0; q < H1_ / 4; ++q) {
                const f32x4 v = p4[q];
                const f32x2 h01 = {v.x, v.y};
                const f32x2 h23 = {v.z, v.w};
                PKFMA(E, w2a[2 * q],     h01);
                PKFMA(F, w2a[2 * q + 1], h23);
            }
            const f32x4* q4 = reinterpret_cast<const f32x4*>(sh2[wid][par ^ 1]);
            #pragma unroll
            for (int q = 0; q < H2_ / 4; ++q) {
                const f32x4 v = q4[q];
                const f32x2 h01 = {v.x, v.y};
                const f32x2 h23 = {v.z, v.w};
                PKFMA(E, w2b[2 * q],     h01);
                PKFMA(F, w2b[2 * q + 1], h23);
            }
        }
        const float d2 = (E.x + E.y) + (F.x + F.y);

        const float s2 = __builtin_fmaf(sc2c, sig_core(d2), of2c);
        const float iv = __shfl(s2, u2);
        const float fv = __shfl(s2, u2 + 16);
        const float gv = __shfl(s2, u2 + 32);
        const float ov = __shfl(s2, u2 + 48);

        c2 = __builtin_fmaf(fv, c2, iv * gv);
        const float tc2 = __builtin_fmaf(2.0f, sig_core(TWOLOG2E * c2), -1.0f);
        const float h2v = ov * tc2;                 // h2_t[u2], replicated x4

        if (lane < H2_) sh2[wid][par][lane] = h2v;  // consumed next step
        FENCE_SW();   // step boundary: no cross-step LDS reorder (zero instr)

        return wout * h2v;   // y partial; reduce later
    };

    f32x4 xv = xr4[0];
    #pragma unroll 1
    for (int t4 = 0; t4 < T_ / 4; ++t4) {
        const int nx = (t4 + 1 < T_ / 4) ? (t4 + 1) : t4;
        const f32x4 xn = xr4[nx];     // prefetch next 4 inputs (never drained mid-loop)

        float p0 = step(xv.x, 0);
        float p1 = step(xv.y, 1);
        float p2 = step(xv.z, 0);
        float p3 = step(xv.w, 1);

        // 4 interleaved 16-lane xor reductions (ILP 4)
        #pragma unroll
        for (int off = 1; off <= 8; off <<= 1) {
            p0 += __shfl_xor(p0, off);
            p1 += __shfl_xor(p1, off);
            p2 += __shfl_xor(p2, off);
            p3 += __shfl_xor(p3, off);
        }

        if (lane == 0) {
            f32x4 yv = {p0 + bout, p1 + bout, p2 + bout, p3 + bout};
            *reinterpret_cast<f32x4*>(orow + 4 * t4) = yv;
        }
        xv = xn;
    }
}

extern "C" void kernel_launch(void* const* d_in, const int* in_sizes, int n_in,
                              void* d_out, int out_size, void* d_ws, size_t ws_size,
                              hipStream_t stream) {
    const float* xp     = (const float*)d_in[0];
    const float* W_ih1  = (const float*)d_in[1];
    const float* W_hh1  = (const float*)d_in[2];
    const float* b_ih1  = (const float*)d_in[3];
    const float* b_hh1  = (const float*)d_in[4];
    const float* W_ih2  = (const float*)d_in[5];
    const float* W_hh2  = (const float*)d_in[6];
    const float* b_ih2  = (const float*)d_in[7];
    const float* b_hh2  = (const float*)d_in[8];
    const float* W_out  = (const float*)d_in[9];
    const float* b_out  = (const float*)d_in[10];
    float* out = (float*)d_out;
    float* ws  = (float*)d_ws;

    prescale_kernel<<<(WS_N + 255) / 256, 256, 0, stream>>>(
        W_ih1, W_hh1, b_ih1, b_hh1, W_ih2, W_hh2, b_ih2, b_hh2, ws);

    dim3 grid(B_ / RPB);
    dim3 block(64 * RPB);
    lstm_deep_kernel<<<grid, block, 0, stream>>>(xp, ws, W_out, b_out, out);
}

// Round 11
// 2543.494 us; speedup vs baseline: 5.1520x; 5.1520x over previous
//
#include <hip/hip_runtime.h>

#define B_  4096
#define T_  2048
#define H1_ 32
#define H2_ 16
#define RPB 4   // waves per 256-thread block; each wave owns 2 independent rows

#define LOG2E     1.44269504088896340736f
#define TWOLOG2E  2.88539008177792681472f

typedef float f32x2 __attribute__((ext_vector_type(2)));
typedef float f32x4 __attribute__((ext_vector_type(4)));

// packed fp32 fma (R5-proven exact; lowers to v_pk_fma_f32)
#if defined(__has_builtin)
#if __has_builtin(__builtin_elementwise_fma)
#define PKFMA(acc, a, b) (acc) = __builtin_elementwise_fma((a), (b), (acc))
#endif
#endif
#ifndef PKFMA
#define PKFMA(acc, a, b) (acc) = (a) * (b) + (acc)
#endif

// Wave-local LDS ordering fences (R9-proven correct, replaces __syncthreads):
// FENCE_HW: compiler memory fence + lgkmcnt(0) wait (DS writes complete before
//           later ds_reads). No s_barrier, no vmcnt drain.
// FENCE_SW: zero-instruction compiler fence (stops cross-step LDS reordering).
#define FENCE_HW() asm volatile("s_waitcnt lgkmcnt(0)" ::: "memory")
#define FENCE_SW() asm volatile("" ::: "memory")

__device__ __forceinline__ float sig_core(float z) {
    return __builtin_amdgcn_rcpf(1.0f + __builtin_amdgcn_exp2f(-z));
}

// ---- ws layout (floats), all pre-scaled by log2e / 2log2e ----
#define WS_W1   0
#define WS_W2A  4096
#define WS_W2B  6144
#define WS_WX   7168
#define WS_B1   7296
#define WS_B2   7424
#define WS_N    7488

// layer1 gate rows: [0,32)=i [32,64)=f [64,96)=g(tanh) [96,128)=o
__device__ __forceinline__ float scale1(int r) {
    return (r >= 64 && r < 96) ? TWOLOG2E : LOG2E;
}
// layer2 gate rows: [0,16)=i [16,32)=f [32,48)=g(tanh) [48,64)=o
__device__ __forceinline__ float scale2(int r) {
    return ((r >> 4) == 2) ? TWOLOG2E : LOG2E;
}

__global__ __launch_bounds__(256) void prescale_kernel(
    const float* __restrict__ W_ih1, const float* __restrict__ W_hh1,
    const float* __restrict__ b_ih1, const float* __restrict__ b_hh1,
    const float* __restrict__ W_ih2, const float* __restrict__ W_hh2,
    const float* __restrict__ b_ih2, const float* __restrict__ b_hh2,
    float* __restrict__ ws)
{
    const int i = blockIdx.x * 256 + threadIdx.x;
    if (i >= WS_N) return;
    float v;
    if (i < WS_W2A) {                       // W_hh1
        v = W_hh1[i] * scale1(i >> 5);
    } else if (i < WS_W2B) {                // W_ih2
        const int j = i - WS_W2A;
        v = W_ih2[j] * scale2(j >> 5);
    } else if (i < WS_WX) {                 // W_hh2
        const int j = i - WS_W2B;
        v = W_hh2[j] * scale2(j >> 4);
    } else if (i < WS_B1) {                 // W_ih1
        const int r = i - WS_WX;
        v = W_ih1[r] * scale1(r);
    } else if (i < WS_B2) {                 // b1 fused
        const int r = i - WS_B1;
        v = (b_ih1[r] + b_hh1[r]) * scale1(r);
    } else {                                // b2 fused
        const int r = i - WS_B2;
        v = (b_ih2[r] + b_hh2[r]) * scale2(r);
    }
    ws[i] = v;
}

__global__ __launch_bounds__(64 * RPB, 2) void lstm_deep_kernel(
    const float* __restrict__ x,
    const float* __restrict__ ws,     // pre-scaled weights/biases
    const float* __restrict__ W_out,
    const float* __restrict__ b_out,
    float* __restrict__ out)
{
    const int tid  = threadIdx.x;
    const int lane = tid & 63;
    const int wid  = tid >> 6;                        // wave within block
    const int row0 = (blockIdx.x * RPB + wid) * 2;    // 2 rows per wave
    const int row1 = row0 + 1;

    // per-wave, per-row PRIVATE LDS slices; wave-local fence ordering
    __shared__ __align__(16) float sh1[RPB][2][H1_];
    __shared__ __align__(16) float sh2[RPB][2][2][H2_];

    // ---- per-lane weights from pre-scaled ws (bare loads; L1 remat is cheap
    //      and now amortized over 2 rows) ----
    const int ga = lane;        // layer1 rows: i (low) / f (high)
    const int gb = 64 + lane;   // layer1 rows: g (low, tanh) / o (high)

    const f32x2* W1p  = reinterpret_cast<const f32x2*>(ws + WS_W1);
    const f32x2* W2ap = reinterpret_cast<const f32x2*>(ws + WS_W2A);
    const f32x2* W2bp = reinterpret_cast<const f32x2*>(ws + WS_W2B);

    f32x2 w1a[H1_ / 2], w1b[H1_ / 2];
    #pragma unroll
    for (int j = 0; j < H1_ / 2; ++j) {
        w1a[j] = W1p[ga * (H1_ / 2) + j];
        w1b[j] = W1p[gb * (H1_ / 2) + j];
    }
    f32x2 w2a[H1_ / 2];
    #pragma unroll
    for (int j = 0; j < H1_ / 2; ++j) w2a[j] = W2ap[lane * (H1_ / 2) + j];
    f32x2 w2b[H2_ / 2];
    #pragma unroll
    for (int j = 0; j < H2_ / 2; ++j) w2b[j] = W2bp[lane * (H2_ / 2) + j];

    const float wxa = ws[WS_WX + ga];
    const float wxb = ws[WS_WX + gb];
    const float ba  = ws[WS_B1 + ga];
    const float bb  = ws[WS_B1 + gb];
    const float b2  = ws[WS_B2 + lane];

    // activation combine constants: act = fma(sc, sigmoid_core, of)
    const bool  low  = (lane < 32);
    const int   gt   = lane >> 4;
    const float sc1b = low ? 2.0f : 1.0f;
    const float of1b = low ? -1.0f : 0.0f;
    const float sc2c = (gt == 2) ? 2.0f : 1.0f;
    const float of2c = (gt == 2) ? -1.0f : 0.0f;

    const int   u2   = lane & 15;
    const float wout = W_out[u2];
    const float bout = b_out[0];

    // ---- state (x2 rows) ----
    float c1_0 = 0.0f, c1_1 = 0.0f;   // valid in high lanes (unit lane-32)
    float c2_0 = 0.0f, c2_1 = 0.0f;   // replicated x4 (unit lane&15)
    if (lane < H1_) { sh1[wid][0][lane] = 0.0f; sh1[wid][1][lane] = 0.0f; }
    if (lane < H2_) {
        sh2[wid][0][0][lane] = 0.0f; sh2[wid][0][1][lane] = 0.0f;
        sh2[wid][1][0][lane] = 0.0f; sh2[wid][1][1][lane] = 0.0f;
    }
    FENCE_HW();   // init visible before first-step reads (wave-local)

    const f32x4* __restrict__ xr0  = reinterpret_cast<const f32x4*>(x + (size_t)row0 * T_);
    const f32x4* __restrict__ xr1  = reinterpret_cast<const f32x4*>(x + (size_t)row1 * T_);
    float*       __restrict__ or0  = out + (size_t)row0 * T_;
    float*       __restrict__ or1  = out + (size_t)row1 * T_;

    // one timestep for BOTH rows; returns un-reduced y partials
    auto step2 = [&](float xt0, float xt1, int par, float& yp0, float& yp1) {
        // ---- layer 1 (both rows): 2 gate rows/lane, packed chains ----
        f32x2 A0 = {__builtin_fmaf(wxa, xt0, ba), 0.0f};
        f32x2 B0 = {__builtin_fmaf(wxb, xt0, bb), 0.0f};
        f32x2 A1 = {__builtin_fmaf(wxa, xt1, ba), 0.0f};
        f32x2 B1 = {__builtin_fmaf(wxb, xt1, bb), 0.0f};
        {
            const f32x4* p0 = reinterpret_cast<const f32x4*>(sh1[wid][0]);
            const f32x4* p1 = reinterpret_cast<const f32x4*>(sh1[wid][1]);
            #pragma unroll
            for (int q = 0; q < H1_ / 4; ++q) {
                const f32x4 v0 = p0[q];
                const f32x4 v1 = p1[q];
                const f32x2 a01 = {v0.x, v0.y}, a23 = {v0.z, v0.w};
                const f32x2 b01 = {v1.x, v1.y}, b23 = {v1.z, v1.w};
                PKFMA(A0, w1a[2 * q],     a01);   // weight regs reused by both rows
                PKFMA(A1, w1a[2 * q],     b01);
                PKFMA(B0, w1b[2 * q],     a01);
                PKFMA(B1, w1b[2 * q],     b01);
                PKFMA(A0, w1a[2 * q + 1], a23);
                PKFMA(A1, w1a[2 * q + 1], b23);
                PKFMA(B0, w1b[2 * q + 1], a23);
                PKFMA(B1, w1b[2 * q + 1], b23);
            }
        }
        const float acca0 = A0.x + A0.y, accb0 = B0.x + B0.y;
        const float acca1 = A1.x + A1.y, accb1 = B1.x + B1.y;

        const float sa0 = sig_core(acca0);
        const float sa1 = sig_core(acca1);
        const float sb0 = __builtin_fmaf(sc1b, sig_core(accb0), of1b);
        const float sb1 = __builtin_fmaf(sc1b, sig_core(accb1), of1b);
        const float pv0 = __shfl_xor(sa0 * sb0, 32);
        const float pv1 = __shfl_xor(sa1 * sb1, 32);
        c1_0 = __builtin_fmaf(sa0, c1_0, pv0);
        c1_1 = __builtin_fmaf(sa1, c1_1, pv1);
        const float tc10 = __builtin_fmaf(2.0f, sig_core(TWOLOG2E * c1_0), -1.0f);
        const float tc11 = __builtin_fmaf(2.0f, sig_core(TWOLOG2E * c1_1), -1.0f);
        const float h1n0 = sb0 * tc10;   // valid lanes 32..63
        const float h1n1 = sb1 * tc11;

        if (lane >= 32) {
            sh1[wid][0][lane - 32] = h1n0;
            sh1[wid][1][lane - 32] = h1n1;
        }
        FENCE_HW();   // both sh1 writes complete; no layer-2 read hoisted above

        // ---- layer 2 (both rows): 1 gate row/lane ----
        f32x2 E0 = {b2, 0.0f}, F0 = {0.0f, 0.0f};
        f32x2 E1 = {b2, 0.0f}, F1 = {0.0f, 0.0f};
        {
            const f32x4* p0 = reinterpret_cast<const f32x4*>(sh1[wid][0]);
            const f32x4* p1 = reinterpret_cast<const f32x4*>(sh1[wid][1]);
            #pragma unroll
            for (int q = 0; q < H1_ / 4; ++q) {
                const f32x4 v0 = p0[q];
                const f32x4 v1 = p1[q];
                const f32x2 va01 = {v0.x, v0.y}, va23 = {v0.z, v0.w};
                const f32x2 vb01 = {v1.x, v1.y}, vb23 = {v1.z, v1.w};
                PKFMA(E0, w2a[2 * q],     va01);
                PKFMA(E1, w2a[2 * q],     vb01);
                PKFMA(F0, w2a[2 * q + 1], va23);
                PKFMA(F1, w2a[2 * q + 1], vb23);
            }
            const f32x4* q0 = reinterpret_cast<const f32x4*>(sh2[wid][0][par ^ 1]);
            const f32x4* q1 = reinterpret_cast<const f32x4*>(sh2[wid][1][par ^ 1]);
            #pragma unroll
            for (int q = 0; q < H2_ / 4; ++q) {
                const f32x4 v0 = q0[q];
                const f32x4 v1 = q1[q];
                const f32x2 va01 = {v0.x, v0.y}, va23 = {v0.z, v0.w};
                const f32x2 vb01 = {v1.x, v1.y}, vb23 = {v1.z, v1.w};
                PKFMA(E0, w2b[2 * q],     va01);
                PKFMA(E1, w2b[2 * q],     vb01);
                PKFMA(F0, w2b[2 * q + 1], va23);
                PKFMA(F1, w2b[2 * q + 1], vb23);
            }
        }
        const float d20 = (E0.x + E0.y) + (F0.x + F0.y);
        const float d21 = (E1.x + E1.y) + (F1.x + F1.y);

        const float s20 = __builtin_fmaf(sc2c, sig_core(d20), of2c);
        const float s21 = __builtin_fmaf(sc2c, sig_core(d21), of2c);
        const float iv0 = __shfl(s20, u2),      iv1 = __shfl(s21, u2);
        const float fv0 = __shfl(s20, u2 + 16), fv1 = __shfl(s21, u2 + 16);
        const float gv0 = __shfl(s20, u2 + 32), gv1 = __shfl(s21, u2 + 32);
        const float ov0 = __shfl(s20, u2 + 48), ov1 = __shfl(s21, u2 + 48);

        c2_0 = __builtin_fmaf(fv0, c2_0, iv0 * gv0);
        c2_1 = __builtin_fmaf(fv1, c2_1, iv1 * gv1);
        const float tc20 = __builtin_fmaf(2.0f, sig_core(TWOLOG2E * c2_0), -1.0f);
        const float tc21 = __builtin_fmaf(2.0f, sig_core(TWOLOG2E * c2_1), -1.0f);
        const float h2v0 = ov0 * tc20;   // replicated x4
        const float h2v1 = ov1 * tc21;

        if (lane < H2_) {
            sh2[wid][0][par][lane] = h2v0;
            sh2[wid][1][par][lane] = h2v1;
        }
        FENCE_SW();   // step boundary: no cross-step LDS reorder (zero instr)

        yp0 = wout * h2v0;
        yp1 = wout * h2v1;
    };

    f32x4 xv0 = xr0[0];
    f32x4 xv1 = xr1[0];
    #pragma unroll 1
    for (int t4 = 0; t4 < T_ / 4; ++t4) {
        const int nx = (t4 + 1 < T_ / 4) ? (t4 + 1) : t4;
        const f32x4 xn0 = xr0[nx];    // prefetch next 4 inputs, both rows
        const f32x4 xn1 = xr1[nx];

        float p00, p10, p01, p11, p02, p12, p03, p13;
        step2(xv0.x, xv1.x, 0, p00, p10);
        step2(xv0.y, xv1.y, 1, p01, p11);
        step2(xv0.z, xv1.z, 0, p02, p12);
        step2(xv0.w, xv1.w, 1, p03, p13);

        // 8 interleaved 16-lane xor reductions (ILP 8)
        #pragma unroll
        for (int off = 1; off <= 8; off <<= 1) {
            p00 += __shfl_xor(p00, off);  p10 += __shfl_xor(p10, off);
            p01 += __shfl_xor(p01, off);  p11 += __shfl_xor(p11, off);
            p02 += __shfl_xor(p02, off);  p12 += __shfl_xor(p12, off);
            p03 += __shfl_xor(p03, off);  p13 += __shfl_xor(p13, off);
        }

        if (lane == 0) {
            f32x4 y0 = {p00 + bout, p01 + bout, p02 + bout, p03 + bout};
            f32x4 y1 = {p10 + bout, p11 + bout, p12 + bout, p13 + bout};
            *reinterpret_cast<f32x4*>(or0 + 4 * t4) = y0;
            *reinterpret_cast<f32x4*>(or1 + 4 * t4) = y1;
        }
        xv0 = xn0;
        xv1 = xn1;
    }
}

extern "C" void kernel_launch(void* const* d_in, const int* in_sizes, int n_in,
                              void* d_out, int out_size, void* d_ws, size_t ws_size,
                              hipStream_t stream) {
    const float* xp     = (const float*)d_in[0];
    const float* W_ih1  = (const float*)d_in[1];
    const float* W_hh1  = (const float*)d_in[2];
    const float* b_ih1  = (const float*)d_in[3];
    const float* b_hh1  = (const float*)d_in[4];
    const float* W_ih2  = (const float*)d_in[5];
    const float* W_hh2  = (const float*)d_in[6];
    const float* b_ih2  = (const float*)d_in[7];
    const float* b_hh2  = (const float*)d_in[8];
    const float* W_out  = (const float*)d_in[9];
    const float* b_out  = (const float*)d_in[10];
    float* out = (float*)d_out;
    float* ws  = (float*)d_ws;

    prescale_kernel<<<(WS_N + 255) / 256, 256, 0, stream>>>(
        W_ih1, W_hh1, b_ih1, b_hh1, W_ih2, W_hh2, b_ih2, b_hh2, ws);

    dim3 grid(B_ / (RPB * 2));
    dim3 block(64 * RPB);
    lstm_deep_kernel<<<grid, block, 0, stream>>>(xp, ws, W_out, b_out, out);
}